// Round 8
// baseline (281.739 us; speedup 1.0000x reference)
//
#include <hip/hip_runtime.h>

// compute_threebody_indices for MatterSim on gfx950 — v8 (MEASUREMENT ROUND).
// Structure = v2 byte-exact (the 244.1us best), with kD launched TWICE.
// kD is idempotent (pure function of inputs + workspace), so correctness is
// unaffected; dur_new - dur_v2 ~= kD_cost + one dispatch boundary. This
// decomposes the 40-60us budget hole that four blind optimization rounds
// (v4/v5/v6b/v7, all +12..18us) failed to locate.
//
// Outputs (int32, concatenated flat in d_out):
//   [0, 2T)                       bond_indices [T,2]  (pairs of ORIGINAL bond ids)
//   [2T, 2T+n_bond)               n_triple_ij
//   [.., +n_atom)                 n_triple_i
//   [.., +n_struct)               n_triple_s

#define CUTOFF 0.8f
#define NATOM_C 100000
#define MAXD 256   // max kept bonds per atom; actual max ~45 (Poisson mean ~16)

// ---- K0: init per-atom ranges to empty + zero degree accumulators ----
__global__ void k0_init(int* wstart, int* wend, int* deg, int n_atom) {
    int i = blockIdx.x * blockDim.x + threadIdx.x;
    if (i < n_atom) { wstart[i] = 0; wend[i] = 0; deg[i] = 0; }
}

// ---- KA: segment boundaries + kept-degree count on sorted bond_src ----
__global__ void kA_bounds_deg(const int* __restrict__ src, const float* __restrict__ len,
                              int* __restrict__ wstart, int* __restrict__ wend,
                              int* __restrict__ deg, int n_bond) {
    int i = blockIdx.x * blockDim.x + threadIdx.x;
    int lane = threadIdx.x & 63;
    bool valid = i < n_bond;
    int a = -1;
    bool kept = false;
    if (valid) {
        a = src[i];
        if (i == 0 || src[i - 1] != a) wstart[a] = i;
        if (i == n_bond - 1 || src[i + 1] != a) wend[a] = i + 1;
        kept = (len[i] <= CUTOFF);
    }
    unsigned long long keptB = __ballot(kept);
    int ap = __shfl_up(a, 1);
    bool head = (lane == 0) || (ap != a);
    unsigned long long headB = __ballot(head);
    unsigned long long nextHeads = (headB >> 1) >> lane;   // heads strictly above
    bool tail = (lane == 63) || ((nextHeads & 1ull) != 0ull);
    if (tail && valid) {
        unsigned long long below = (lane == 63) ? ~0ull : ((2ull << lane) - 1ull);
        int runStart = 63 - __clzll(headB & below);        // headB bit0 always set
        unsigned long long runMask = below & ~((1ull << runStart) - 1ull);
        int cnt = __popcll(keptB & runMask);
        if (cnt) atomicAdd(&deg[a], cnt);
    }
}

// ---- KB: per-block (1024-elem chunk) exclusive scan of d*(d-1);
//          also writes n_triple_i output. Block totals to bsums. ----
__global__ void kB_scan(const int* __restrict__ deg, int* __restrict__ out_i,
                        int* __restrict__ exsc, int* __restrict__ bsums, int n) {
    __shared__ int tmp[256];
    int t = threadIdx.x;
    int base = blockIdx.x * 1024 + t * 4;
    int v0 = 0, v1 = 0, v2 = 0, v3 = 0;
    if (base     < n) { int d = deg[base];     v0 = d * (d - 1); out_i[base]     = v0; }
    if (base + 1 < n) { int d = deg[base + 1]; v1 = d * (d - 1); out_i[base + 1] = v1; }
    if (base + 2 < n) { int d = deg[base + 2]; v2 = d * (d - 1); out_i[base + 2] = v2; }
    if (base + 3 < n) { int d = deg[base + 3]; v3 = d * (d - 1); out_i[base + 3] = v3; }
    int s = v0 + v1 + v2 + v3;
    tmp[t] = s;
    __syncthreads();
    for (int off = 1; off < 256; off <<= 1) {
        int v = (t >= off) ? tmp[t - off] : 0;
        __syncthreads();
        tmp[t] += v;
        __syncthreads();
    }
    int excl = tmp[t] - s;                       // exclusive prefix within block
    if (base     < n) exsc[base]     = excl;
    if (base + 1 < n) exsc[base + 1] = excl + v0;
    if (base + 2 < n) exsc[base + 2] = excl + v0 + v1;
    if (base + 3 < n) exsc[base + 3] = excl + v0 + v1 + v2;
    if (t == 255) bsums[blockIdx.x] = tmp[255];  // block total
}

// ---- KC: single-block exclusive scan of block sums (in place) + n_triple_s ----
__global__ void kC_scan2(int* __restrict__ bsums, const int* __restrict__ exsc,
                         const int* __restrict__ n_atoms_arr, int* __restrict__ out_s,
                         int nb, int n_atom, int n_struct) {
    const int B = 256;
    __shared__ int sums[B];
    int t = threadIdx.x;
    int chunk = (nb + B - 1) / B;
    int lo = t * chunk; if (lo > nb) lo = nb;
    int hi = lo + chunk; if (hi > nb) hi = nb;
    int ssum = 0;
    for (int i = lo; i < hi; i++) ssum += bsums[i];
    sums[t] = ssum;
    __syncthreads();
    for (int off = 1; off < B; off <<= 1) {
        int v = (t >= off) ? sums[t - off] : 0;
        __syncthreads();
        sums[t] += v;
        __syncthreads();
    }
    int run = sums[t] - ssum;
    for (int i = lo; i < hi; i++) { int v = bsums[i]; bsums[i] = run; run += v; }
    if (t == B - 1) { /* total in sums[B-1] */ }
    int total = sums[B - 1];
    __syncthreads();
    if (t == 0) {
        int off = 0, prevA = 0;
        for (int s = 0; s < n_struct; s++) {
            off += n_atoms_arr[s];
            int A = (off >= n_atom) ? total : (exsc[off] + bsums[off >> 10]);
            out_s[s] = A - prevA;
            prevA = A;
        }
    }
}

// ---- KD: wave-per-atom triple enumeration + n_triple_ij (4 atoms / block) ----
__global__ void kD_enum(const float* __restrict__ len, const int* __restrict__ wstart,
                        const int* __restrict__ wend, const int* __restrict__ exsc,
                        const int* __restrict__ bsums,
                        int4* __restrict__ out4, int* __restrict__ out_ij,
                        int n_atom) {
    __shared__ int keptIds[4 * MAXD];
    int wave = threadIdx.x >> 6;
    int lane = threadIdx.x & 63;
    int a = blockIdx.x * 4 + wave;
    int* my = &keptIds[wave * MAXD];
    if (a >= n_atom) return;
    int s = wstart[a], e = wend[a];
    int d = 0;
    // order-preserving compaction of kept ORIGINAL bond ids into LDS
    for (int base = s; base < e; base += 64) {
        int idx = base + lane;
        bool m = (idx < e) && (len[idx] <= CUTOFF);
        unsigned long long bal = __ballot(m);
        int pos = d + __popcll(bal & ((1ull << lane) - 1ull));
        if (m && pos < MAXD) my[pos] = idx;
        d += __popcll(bal);
    }
    int dm1 = d - 1;
    for (int idx = s + lane; idx < e; idx += 64)
        out_ij[idx] = (len[idx] <= CUTOFF) ? dm1 : 0;   // len L1-hot
    if (d >= 2) {
        unsigned udm1 = (unsigned)dm1;
        unsigned nP = ((unsigned)(d * dm1)) >> 1;        // pairs of triples
        int b4 = (exsc[a] + bsums[a >> 10]) >> 1;        // tstart[a]/2, exact
        for (unsigned p = lane; p < nP; p += 64) {
            unsigned t0 = 2u * p;
            unsigned j  = t0 / udm1;                     // one div per PAIR
            unsigned kp = t0 - j * udm1;
            unsigned j1 = j, kp1 = kp + 1;
            if (kp1 == udm1) { j1++; kp1 = 0; }          // t0+1 rollover
            unsigned k0 = kp  + (kp  >= j  ? 1u : 0u);   // skip k == j
            unsigned k1 = kp1 + (kp1 >= j1 ? 1u : 0u);
            out4[b4 + p] = make_int4(my[j], my[k0], my[j1], my[k1]);
        }
    }
}

// ================================ launch ================================
extern "C" void kernel_launch(void* const* d_in, const int* in_sizes, int n_in,
                              void* d_out, int out_size, void* d_ws, size_t ws_size,
                              hipStream_t stream) {
    const int*   bond_src    = (const int*)d_in[0];
    const float* bond_len    = (const float*)d_in[1];
    const int*   n_atoms_arr = (const int*)d_in[2];
    int n_bond   = in_sizes[0];
    int n_struct = in_sizes[2];
    const int n_atom = NATOM_C;
    int T2 = out_size - n_bond - n_atom - n_struct;   // = 2*T

    int nblk_scan = (n_atom + 1023) / 1024;

    // workspace (ints): wstart | wend | deg | tstart/exsc[n_atom] | bsums[nblk]
    int* ws     = (int*)d_ws;
    int* wstart = ws;
    int* wend   = ws + n_atom;
    int* deg    = ws + 2 * n_atom;
    int* exsc   = ws + 3 * n_atom;
    int* bsums  = exsc + n_atom;

    int*  out       = (int*)d_out;
    int4* out_pairs = (int4*)out;          // [T/2] rows of 2 triples, 16B-aligned
    int*  out_ij    = out + T2;
    int*  out_i     = out_ij + n_bond;
    int*  out_s     = out_i + n_atom;

    k0_init      <<<(n_atom + 255) / 256, 256, 0, stream>>>(wstart, wend, deg, n_atom);
    kA_bounds_deg<<<(n_bond + 255) / 256, 256, 0, stream>>>(bond_src, bond_len, wstart, wend, deg, n_bond);
    kB_scan      <<<nblk_scan, 256, 0, stream>>>(deg, out_i, exsc, bsums, n_atom);
    kC_scan2     <<<1, 256, 0, stream>>>(bsums, exsc, n_atoms_arr, out_s, nblk_scan, n_atom, n_struct);
    kD_enum      <<<(n_atom + 3) / 4, 256, 0, stream>>>(bond_len, wstart, wend, exsc, bsums, out_pairs, out_ij, n_atom);
    // MEASUREMENT: duplicate kD (idempotent). dur - dur_v2 ~= kD + boundary.
    kD_enum      <<<(n_atom + 3) / 4, 256, 0, stream>>>(bond_len, wstart, wend, exsc, bsums, out_pairs, out_ij, n_atom);
}

// Round 9
// 246.163 us; speedup vs baseline: 1.1445x; 1.1445x over previous
//
#include <hip/hip_runtime.h>

// compute_threebody_indices for MatterSim on gfx950 — v9 (4 free-running kernels).
//
// Measured decomposition (v8 A/B): kD ~= 33us (write floor 205MB@6.7TB/s = 31us
// -> kD is AT its roofline); dispatch boundary ~= 4.6us; fill (harness) 127us;
// ~40us fixed graph overhead. Only clean lever left: drop the kC dispatch.
//
// v9 = v2's proven k0/kA/kB internals + v8's proven kD body, with kC folded
// into kD via v7's HW-verified wave_prefix_sum over raw tile totals (kB leaves
// bsums unscanned; each kD wave sums bsums[0..tile) itself: 98 L2-hot ints,
// 2 guarded loads + 6-step shfl_xor butterfly; block 0 wave 0 emits n_triple_s).
// Ordering comes free from the kB->kD dispatch boundary. No new sync anywhere.
//
// Outputs (int32, concatenated flat in d_out):
//   [0, 2T)                       bond_indices [T,2]  (pairs of ORIGINAL bond ids)
//   [2T, 2T+n_bond)               n_triple_ij
//   [.., +n_atom)                 n_triple_i
//   [.., +n_struct)               n_triple_s

#define CUTOFF 0.8f
#define NATOM_C 100000
#define MAXD 256   // max kept bonds per atom; actual max ~45 (Poisson mean ~16)

// ---- K0: init per-atom ranges to empty + zero degree accumulators ----
__global__ void k0_init(int* wstart, int* wend, int* deg, int n_atom) {
    int i = blockIdx.x * blockDim.x + threadIdx.x;
    if (i < n_atom) { wstart[i] = 0; wend[i] = 0; deg[i] = 0; }
}

// ---- KA: segment boundaries + kept-degree count on sorted bond_src ----
// Runs of equal src are contiguous; within a wave, count kept bonds per run
// with popcount over the ballot and do ONE atomicAdd per run-tail. Partial
// runs at wave edges just contribute partial counts (atomics sum). [v2-exact]
__global__ void kA_bounds_deg(const int* __restrict__ src, const float* __restrict__ len,
                              int* __restrict__ wstart, int* __restrict__ wend,
                              int* __restrict__ deg, int n_bond) {
    int i = blockIdx.x * blockDim.x + threadIdx.x;
    int lane = threadIdx.x & 63;
    bool valid = i < n_bond;
    int a = -1;
    bool kept = false;
    if (valid) {
        a = src[i];
        if (i == 0 || src[i - 1] != a) wstart[a] = i;
        if (i == n_bond - 1 || src[i + 1] != a) wend[a] = i + 1;
        kept = (len[i] <= CUTOFF);
    }
    unsigned long long keptB = __ballot(kept);
    int ap = __shfl_up(a, 1);
    bool head = (lane == 0) || (ap != a);
    unsigned long long headB = __ballot(head);
    unsigned long long nextHeads = (headB >> 1) >> lane;   // heads strictly above
    bool tail = (lane == 63) || ((nextHeads & 1ull) != 0ull);
    if (tail && valid) {
        unsigned long long below = (lane == 63) ? ~0ull : ((2ull << lane) - 1ull);
        int runStart = 63 - __clzll(headB & below);        // headB bit0 always set
        unsigned long long runMask = below & ~((1ull << runStart) - 1ull);
        int cnt = __popcll(keptB & runMask);
        if (cnt) atomicAdd(&deg[a], cnt);
    }
}

// ---- KB: per-tile (1024 atoms) exclusive scan of d*(d-1); n_triple_i out.
//          bsums keeps RAW tile totals (kD derives prefixes itself). ----
__global__ void kB_scan(const int* __restrict__ deg, int* __restrict__ out_i,
                        int* __restrict__ exsc, int* __restrict__ bsums, int n) {
    __shared__ int tmp[256];
    int t = threadIdx.x;
    int base = blockIdx.x * 1024 + t * 4;
    int v0 = 0, v1 = 0, v2 = 0, v3 = 0;
    if (base + 3 < n) {
        int4 d4 = *(const int4*)(deg + base);
        v0 = d4.x * (d4.x - 1); v1 = d4.y * (d4.y - 1);
        v2 = d4.z * (d4.z - 1); v3 = d4.w * (d4.w - 1);
        *(int4*)(out_i + base) = make_int4(v0, v1, v2, v3);
    } else {
        if (base     < n) { int d = deg[base];     v0 = d * (d - 1); out_i[base]     = v0; }
        if (base + 1 < n) { int d = deg[base + 1]; v1 = d * (d - 1); out_i[base + 1] = v1; }
        if (base + 2 < n) { int d = deg[base + 2]; v2 = d * (d - 1); out_i[base + 2] = v2; }
        if (base + 3 < n) { int d = deg[base + 3]; v3 = d * (d - 1); out_i[base + 3] = v3; }
    }
    int s = v0 + v1 + v2 + v3;
    tmp[t] = s;
    __syncthreads();
    for (int off = 1; off < 256; off <<= 1) {
        int v = (t >= off) ? tmp[t - off] : 0;
        __syncthreads();
        tmp[t] += v;
        __syncthreads();
    }
    int excl = tmp[t] - s;                       // exclusive prefix within tile
    if (base     < n) exsc[base]     = excl;
    if (base + 1 < n) exsc[base + 1] = excl + v0;
    if (base + 2 < n) exsc[base + 2] = excl + v0 + v1;
    if (base + 3 < n) exsc[base + 3] = excl + v0 + v1 + v2;
    if (t == 255) bsums[blockIdx.x] = tmp[255];  // RAW tile total
}

// wave-uniform sum of bsums[0..K) (K <= 98: 2 guarded loads + butterfly)
__device__ __forceinline__ int wave_prefix_sum(const int* __restrict__ bsums,
                                               int K, int lane) {
    int x = 0;
    for (int l = lane; l < K; l += 64) x += bsums[l];
#pragma unroll
    for (int m = 1; m < 64; m <<= 1) x += __shfl_xor(x, m);
    return x;    // same value in all 64 lanes
}

// ---- KD: wave-per-atom triple enumeration + n_triple_ij (4 atoms / block);
//          per-wave bsums reduction replaces kC; block 0 emits n_triple_s.
//          Body = v8's proven 33us version; additions are v7-HW-verified. ----
__global__ void kD_enum(const float* __restrict__ len, const int* __restrict__ wstart,
                        const int* __restrict__ wend, const int* __restrict__ exsc,
                        const int* __restrict__ bsums, const int* __restrict__ n_atoms_arr,
                        int4* __restrict__ out4, int* __restrict__ out_ij,
                        int* __restrict__ out_s,
                        int n_atom, int ntiles, int n_struct) {
    __shared__ int keptIds[4 * MAXD];
    int wave = threadIdx.x >> 6;
    int lane = threadIdx.x & 63;
    int a = blockIdx.x * 4 + wave;
    int* my = &keptIds[wave * MAXD];

    // ---- n_triple_s (block 0, wave 0; bsums/exsc ready via dispatch boundary) ----
    if (blockIdx.x == 0 && wave == 0) {
        int off = 0, prevA = 0;
        for (int s2 = 0; s2 < n_struct; s2++) {
            off += n_atoms_arr[s2];
            int A;
            if (off >= n_atom) A = wave_prefix_sum(bsums, ntiles, lane);
            else               A = wave_prefix_sum(bsums, off >> 10, lane) + exsc[off];
            if (lane == 0) out_s[s2] = A - prevA;
            prevA = A;
        }
    }

    if (a >= n_atom) return;
    int s = wstart[a], e = wend[a];
    int d = 0;
    // order-preserving compaction of kept ORIGINAL bond ids into LDS
    for (int base = s; base < e; base += 64) {
        int idx = base + lane;
        bool m = (idx < e) && (len[idx] <= CUTOFF);
        unsigned long long bal = __ballot(m);
        int pos = d + __popcll(bal & ((1ull << lane) - 1ull));
        if (m && pos < MAXD) my[pos] = idx;
        d += __popcll(bal);
    }
    int dm1 = d - 1;
    for (int idx = s + lane; idx < e; idx += 64)
        out_ij[idx] = (len[idx] <= CUTOFF) ? dm1 : 0;   // len L1-hot
    if (d >= 2) {
        // tstart[a] = exsc[a] + sum of raw tile totals before a's tile
        int pref = wave_prefix_sum(bsums, a >> 10, lane);
        int b4 = (exsc[a] + pref) >> 1;                  // tstart[a]/2, exact
        unsigned udm1 = (unsigned)dm1;
        unsigned nP = ((unsigned)(d * dm1)) >> 1;        // pairs of triples
        for (unsigned p = lane; p < nP; p += 64) {
            unsigned t0 = 2u * p;
            unsigned j  = t0 / udm1;                     // one div per PAIR
            unsigned kp = t0 - j * udm1;
            unsigned j1 = j, kp1 = kp + 1;
            if (kp1 == udm1) { j1++; kp1 = 0; }          // t0+1 rollover
            unsigned k0 = kp  + (kp  >= j  ? 1u : 0u);   // skip k == j
            unsigned k1 = kp1 + (kp1 >= j1 ? 1u : 0u);
            out4[b4 + p] = make_int4(my[j], my[k0], my[j1], my[k1]);
        }
    }
}

// ================================ launch ================================
extern "C" void kernel_launch(void* const* d_in, const int* in_sizes, int n_in,
                              void* d_out, int out_size, void* d_ws, size_t ws_size,
                              hipStream_t stream) {
    const int*   bond_src    = (const int*)d_in[0];
    const float* bond_len    = (const float*)d_in[1];
    const int*   n_atoms_arr = (const int*)d_in[2];
    int n_bond   = in_sizes[0];
    int n_struct = in_sizes[2];
    const int n_atom = NATOM_C;
    int T2 = out_size - n_bond - n_atom - n_struct;   // = 2*T

    int ntiles = (n_atom + 1023) / 1024;              // 98

    // workspace (ints): wstart | wend | deg | exsc[n_atom] | bsums[ntiles]
    int* ws     = (int*)d_ws;
    int* wstart = ws;
    int* wend   = ws + n_atom;
    int* deg    = ws + 2 * n_atom;
    int* exsc   = ws + 3 * n_atom;
    int* bsums  = exsc + n_atom;

    int*  out       = (int*)d_out;
    int4* out_pairs = (int4*)out;          // [T/2] rows of 2 triples, 16B-aligned
    int*  out_ij    = out + T2;
    int*  out_i     = out_ij + n_bond;
    int*  out_s     = out_i + n_atom;

    k0_init      <<<(n_atom + 255) / 256, 256, 0, stream>>>(wstart, wend, deg, n_atom);
    kA_bounds_deg<<<(n_bond + 255) / 256, 256, 0, stream>>>(bond_src, bond_len, wstart, wend, deg, n_bond);
    kB_scan      <<<ntiles, 256, 0, stream>>>(deg, out_i, exsc, bsums, n_atom);
    kD_enum      <<<(n_atom + 3) / 4, 256, 0, stream>>>(bond_len, wstart, wend, exsc, bsums,
                                                        n_atoms_arr, out_pairs, out_ij, out_s,
                                                        n_atom, ntiles, n_struct);
}